// Round 1
// baseline (1866.011 us; speedup 1.0000x reference)
//
#include <hip/hip_runtime.h>
#include <math.h>

#define B_ 8
#define N_ 1024
#define D_ 512
#define H_ 4

// ---- tiled fp32 GEMM config: 128x128 C-tile, K-step 16, 8x8 per thread ----
#define BM 128
#define BN 128
#define BK 16
#define TM 8
#define TN 8
// threads per block = (BM/TM)*(BN/TN) = 256

// Kernel 1: Y[b,h] = x[b] @ W[h]         A:[N,D] row-major, B:[D,D] row-major
__global__ __launch_bounds__(256) void gemm_xw(const float* __restrict__ x,
                                               const float* __restrict__ W,
                                               float* __restrict__ Y) {
    const int bh = blockIdx.z;            // 0..31
    const int b  = bh >> 2, h = bh & 3;
    const int n0 = blockIdx.y * BM;       // N tile
    const int e0 = blockIdx.x * BN;       // output-col tile

    const float* A  = x + (size_t)b * N_ * D_;
    const float* Bm = W + (size_t)h * D_ * D_;
    float*       C  = Y + (size_t)bh * N_ * D_;

    __shared__ float sA[BK][BM + 1];
    __shared__ float sB[BK][BN + 1];

    const int t  = threadIdx.x;
    const int tx = t & 15, ty = t >> 4;

    float acc[TM][TN] = {};

    for (int k0 = 0; k0 < D_; k0 += BK) {
#pragma unroll
        for (int p = 0; p < (BM * BK) / 256; ++p) {
            int idx = t + p * 256;
            int r = idx / BK, c = idx % BK;
            sA[c][r] = A[(size_t)(n0 + r) * D_ + (k0 + c)];
        }
#pragma unroll
        for (int p = 0; p < (BK * BN) / 256; ++p) {
            int idx = t + p * 256;
            int r = idx / BN, c = idx % BN;
            sB[r][c] = Bm[(size_t)(k0 + r) * D_ + (e0 + c)];
        }
        __syncthreads();
#pragma unroll
        for (int k = 0; k < BK; ++k) {
            float a[TM], bb[TN];
#pragma unroll
            for (int i = 0; i < TM; ++i) a[i] = sA[k][ty * TM + i];
#pragma unroll
            for (int j = 0; j < TN; ++j) bb[j] = sB[k][tx * TN + j];
#pragma unroll
            for (int i = 0; i < TM; ++i)
#pragma unroll
                for (int j = 0; j < TN; ++j) acc[i][j] += a[i] * bb[j];
        }
        __syncthreads();
    }
#pragma unroll
    for (int i = 0; i < TM; ++i)
#pragma unroll
        for (int j = 0; j < TN; ++j)
            C[(size_t)(n0 + ty * TM + i) * D_ + (e0 + tx * TN + j)] = acc[i][j];
}

// Kernel 2: S[b,h] = Y[b,h] @ x[b]^T * scale     S[n,m] = sum_e Y[n,e]*x[m,e]
__global__ __launch_bounds__(256) void gemm_yxT(const float* __restrict__ Y,
                                                const float* __restrict__ x,
                                                float* __restrict__ S) {
    const int bh = blockIdx.z;
    const int b  = bh >> 2;
    const int n0 = blockIdx.y * BM;
    const int m0 = blockIdx.x * BN;

    const float* A = Y + (size_t)bh * N_ * D_;
    const float* X = x + (size_t)b * N_ * D_;
    float*       C = S + (size_t)bh * N_ * N_;

    __shared__ float sA[BK][BM + 1];
    __shared__ float sB[BK][BN + 1];

    const int t  = threadIdx.x;
    const int tx = t & 15, ty = t >> 4;
    const float scale = 0.044194173824159216f; // 512^-0.5

    float acc[TM][TN] = {};

    for (int k0 = 0; k0 < D_; k0 += BK) {
#pragma unroll
        for (int p = 0; p < (BM * BK) / 256; ++p) {
            int idx = t + p * 256;
            int r = idx / BK, c = idx % BK;
            sA[c][r] = A[(size_t)(n0 + r) * D_ + (k0 + c)];
        }
        // B[e][m] = x[m][e] ; read contiguous in e for coalescing
#pragma unroll
        for (int p = 0; p < (BK * BN) / 256; ++p) {
            int idx = t + p * 256;
            int m = idx / BK, e = idx % BK;
            sB[e][m] = X[(size_t)(m0 + m) * D_ + (k0 + e)];
        }
        __syncthreads();
#pragma unroll
        for (int k = 0; k < BK; ++k) {
            float a[TM], bb[TN];
#pragma unroll
            for (int i = 0; i < TM; ++i) a[i] = sA[k][ty * TM + i];
#pragma unroll
            for (int j = 0; j < TN; ++j) bb[j] = sB[k][tx * TN + j];
#pragma unroll
            for (int i = 0; i < TM; ++i)
#pragma unroll
                for (int j = 0; j < TN; ++j) acc[i][j] += a[i] * bb[j];
        }
        __syncthreads();
    }
#pragma unroll
    for (int i = 0; i < TM; ++i)
#pragma unroll
        for (int j = 0; j < TN; ++j)
            C[(size_t)(n0 + ty * TM + i) * N_ + (m0 + tx * TN + j)] = acc[i][j] * scale;
}

// Kernel 3: rowwise softmax, in place on S. One block per row of 1024.
__global__ __launch_bounds__(256) void softmax_rows(float* __restrict__ S) {
    const size_t row = blockIdx.x;
    float4* p = (float4*)(S + row * (size_t)N_);
    const int t = threadIdx.x;

    float4 v = p[t];
    float m = fmaxf(fmaxf(v.x, v.y), fmaxf(v.z, v.w));
#pragma unroll
    for (int o = 32; o > 0; o >>= 1) m = fmaxf(m, __shfl_xor(m, o));

    __shared__ float wred[4];
    const int wave = t >> 6, lane = t & 63;
    if (lane == 0) wred[wave] = m;
    __syncthreads();
    m = fmaxf(fmaxf(wred[0], wred[1]), fmaxf(wred[2], wred[3]));

    v.x = __expf(v.x - m);
    v.y = __expf(v.y - m);
    v.z = __expf(v.z - m);
    v.w = __expf(v.w - m);
    float s = v.x + v.y + v.z + v.w;
#pragma unroll
    for (int o = 32; o > 0; o >>= 1) s += __shfl_xor(s, o);
    __syncthreads();
    if (lane == 0) wred[wave] = s;
    __syncthreads();
    s = wred[0] + wred[1] + wred[2] + wred[3];

    const float inv = 1.0f / s;
    v.x *= inv; v.y *= inv; v.z *= inv; v.w *= inv;
    p[t] = v;
}

// Kernel 4: out[b] = 0.25 * sum_h P[b,h] @ x[b]
// Treated as one GEMM with K = H*N = 4096; A[n][k] = P[b, k>>10, n, k&1023],
// B[k][d] = x[b, k&1023, d]. BK=16 tiles never straddle an h boundary.
__global__ __launch_bounds__(256) void gemm_px(const float* __restrict__ P,
                                               const float* __restrict__ x,
                                               float* __restrict__ out) {
    const int b  = blockIdx.z;            // 0..7
    const int n0 = blockIdx.y * BM;       // 0..7 tiles
    const int d0 = blockIdx.x * BN;       // 0..3 tiles

    const float* X = x + (size_t)b * N_ * D_;
    float*       C = out + (size_t)b * N_ * D_;

    __shared__ float sA[BK][BM + 1];
    __shared__ float sB[BK][BN + 1];

    const int t  = threadIdx.x;
    const int tx = t & 15, ty = t >> 4;

    float acc[TM][TN] = {};

    for (int k0 = 0; k0 < H_ * N_; k0 += BK) {
        const int h     = k0 >> 10;
        const int mbase = k0 & (N_ - 1);
        const float* A = P + ((size_t)(b * H_ + h) * N_) * N_;
#pragma unroll
        for (int p = 0; p < (BM * BK) / 256; ++p) {
            int idx = t + p * 256;
            int r = idx / BK, c = idx % BK;
            sA[c][r] = A[(size_t)(n0 + r) * N_ + (mbase + c)];
        }
#pragma unroll
        for (int p = 0; p < (BK * BN) / 256; ++p) {
            int idx = t + p * 256;
            int r = idx / BN, c = idx % BN;
            sB[r][c] = X[(size_t)(mbase + r) * D_ + (d0 + c)];
        }
        __syncthreads();
#pragma unroll
        for (int k = 0; k < BK; ++k) {
            float a[TM], bb[TN];
#pragma unroll
            for (int i = 0; i < TM; ++i) a[i] = sA[k][ty * TM + i];
#pragma unroll
            for (int j = 0; j < TN; ++j) bb[j] = sB[k][tx * TN + j];
#pragma unroll
            for (int i = 0; i < TM; ++i)
#pragma unroll
                for (int j = 0; j < TN; ++j) acc[i][j] += a[i] * bb[j];
        }
        __syncthreads();
    }
#pragma unroll
    for (int i = 0; i < TM; ++i)
#pragma unroll
        for (int j = 0; j < TN; ++j)
            C[(size_t)(n0 + ty * TM + i) * D_ + (d0 + tx * TN + j)] = acc[i][j] * 0.25f;
}

extern "C" void kernel_launch(void* const* d_in, const int* in_sizes, int n_in,
                              void* d_out, int out_size, void* d_ws, size_t ws_size,
                              hipStream_t stream) {
    const float* x = (const float*)d_in[0];   // [8,1024,512]
    const float* W = (const float*)d_in[1];   // [4,512,512]
    float* out = (float*)d_out;               // [8,1024,512]

    // workspace: Y (64 MiB fp32) then S (128 MiB fp32)
    float* Y = (float*)d_ws;
    float* S = Y + (size_t)B_ * H_ * N_ * D_;

    dim3 blk(256);
    gemm_xw <<<dim3(D_ / BN, N_ / BM, B_ * H_), blk, 0, stream>>>(x, W, Y);
    gemm_yxT<<<dim3(N_ / BN, N_ / BM, B_ * H_), blk, 0, stream>>>(Y, x, S);
    softmax_rows<<<dim3(B_ * H_ * N_), blk, 0, stream>>>(S);
    gemm_px <<<dim3(D_ / BN, N_ / BM, B_), blk, 0, stream>>>(S, x, out);
}

// Round 2
// 384.216 us; speedup vs baseline: 4.8567x; 4.8567x over previous
//
#include <hip/hip_runtime.h>
#include <math.h>

#define B_ 8
#define N_ 1024
#define D_ 512
#define H_ 4
#define ND (N_ * D_)      // 524288
#define DD (D_ * D_)      // 262144
#define NN (N_ * N_)      // 1048576

typedef __bf16 bf16;
typedef bf16 bf16x8 __attribute__((ext_vector_type(8)));
typedef bf16 bf16x4 __attribute__((ext_vector_type(4)));
typedef float f32x4 __attribute__((ext_vector_type(4)));

typedef __attribute__((address_space(3))) void lds_void;
typedef __attribute__((address_space(1))) void g_void;

// =====================================================================
// Uniform B^T-form MFMA GEMM core: C[M][Ncols] = A[M][K] * Bt[Ncols][K]^T
// 128x128 C-tile per block (256 threads = 4 waves, each wave 64x64 as
// 4x4 grid of 16x16x32 MFMA tiles). BK = 32. Single-buffered LDS,
// global_load_lds width-16 staging (m97 structure).
// SPLIT: A and B each come as (hi, lo) bf16 pairs; 3-product bf16x3 fp32
// emulation. FOLDH: A's K axis is h*1024+m over P[b][h][n][m]; B's K axis
// ignores h (Bt[d][m] = xT[d][m]).
// EPI 0: store bf16 hi/lo pair (for Y).  EPI 1: store fp32 * scale.
// =====================================================================
template<bool SPLIT, bool FOLDH, int EPI, int LDA, int LDB, int LDC, int KTOT>
__device__ __forceinline__ void gemm_core(
    const bf16* __restrict__ Ah, const bf16* __restrict__ Al,
    const bf16* __restrict__ Bh, const bf16* __restrict__ Bl,
    float* __restrict__ Cf, bf16* __restrict__ Ch, bf16* __restrict__ Cl,
    float scale)
{
    __shared__ bf16 sAh[128 * 32];
    __shared__ bf16 sBh[128 * 32];
    __shared__ bf16 sAl[128 * 32];
    __shared__ bf16 sBl[128 * 32];

    const int n0 = blockIdx.y * 128;   // output row tile
    const int c0 = blockIdx.x * 128;   // output col tile

    const int t = threadIdx.x;
    const int w = t >> 6;              // wave 0..3
    const int l = t & 63;              // lane
    const int lrow = l >> 2;           // staging: sub-row 0..15
    const int lch  = l & 3;            // staging: 16B chunk 0..3
    const int wr = w >> 1, wc = w & 1; // wave's 64x64 quadrant
    const int fr = l & 15;             // fragment row/col
    const int fq = l >> 4;             // fragment quad 0..3

    f32x4 acc[4][4] = {};

    for (int k0 = 0; k0 < KTOT; k0 += 32) {
        int aoff, boff;
        if (FOLDH) {
            const int hh = k0 >> 10;
            const int mm = k0 & (N_ - 1);
            aoff = hh * NN + mm;
            boff = mm;
        } else {
            aoff = k0;
            boff = k0;
        }

        // ---- stage A,B (and lo halves) : global -> LDS, 16B/lane ----
#pragma unroll
        for (int i = 0; i < 2; ++i) {
            const int rb  = w * 2 + i;            // row-block 0..7
            const int row = rb * 16 + lrow;       // 0..127
            {
                const bf16* g = Ah + (size_t)(n0 + row) * LDA + aoff + lch * 8;
                __builtin_amdgcn_global_load_lds((g_void*)g, (lds_void*)(sAh + rb * 512), 16, 0, 0);
            }
            {
                const bf16* g = Bh + (size_t)(c0 + row) * LDB + boff + lch * 8;
                __builtin_amdgcn_global_load_lds((g_void*)g, (lds_void*)(sBh + rb * 512), 16, 0, 0);
            }
            if constexpr (SPLIT) {
                const bf16* ga = Al + (size_t)(n0 + row) * LDA + aoff + lch * 8;
                __builtin_amdgcn_global_load_lds((g_void*)ga, (lds_void*)(sAl + rb * 512), 16, 0, 0);
                const bf16* gb = Bl + (size_t)(c0 + row) * LDB + boff + lch * 8;
                __builtin_amdgcn_global_load_lds((g_void*)gb, (lds_void*)(sBl + rb * 512), 16, 0, 0);
            }
        }
        __syncthreads();

        // ---- fragments from LDS ----
        bf16x8 a_h[4], b_h[4], a_l[4], b_l[4];
#pragma unroll
        for (int i = 0; i < 4; ++i) {
            const int ra = (wr * 64 + i * 16 + fr) * 32 + fq * 8;
            const int rb2 = (wc * 64 + i * 16 + fr) * 32 + fq * 8;
            a_h[i] = *(const bf16x8*)(sAh + ra);
            b_h[i] = *(const bf16x8*)(sBh + rb2);
            if constexpr (SPLIT) {
                a_l[i] = *(const bf16x8*)(sAl + ra);
                b_l[i] = *(const bf16x8*)(sBl + rb2);
            }
        }

        // ---- MFMA ----
#pragma unroll
        for (int i = 0; i < 4; ++i)
#pragma unroll
            for (int j = 0; j < 4; ++j) {
                acc[i][j] = __builtin_amdgcn_mfma_f32_16x16x32_bf16(a_h[i], b_h[j], acc[i][j], 0, 0, 0);
                if constexpr (SPLIT) {
                    acc[i][j] = __builtin_amdgcn_mfma_f32_16x16x32_bf16(a_l[i], b_h[j], acc[i][j], 0, 0, 0);
                    acc[i][j] = __builtin_amdgcn_mfma_f32_16x16x32_bf16(a_h[i], b_l[j], acc[i][j], 0, 0, 0);
                }
            }
        __syncthreads();
    }

    // ---- epilogue: C/D layout col=lane&15, row=quad*4+reg ----
#pragma unroll
    for (int i = 0; i < 4; ++i)
#pragma unroll
        for (int j = 0; j < 4; ++j)
#pragma unroll
            for (int r = 0; r < 4; ++r) {
                const int row = n0 + wr * 64 + i * 16 + fq * 4 + r;
                const int col = c0 + wc * 64 + j * 16 + fr;
                const size_t idx = (size_t)row * LDC + col;
                if constexpr (EPI == 1) {
                    Cf[idx] = acc[i][j][r] * scale;
                } else {
                    const float v = acc[i][j][r];
                    const bf16 hh = (bf16)v;
                    Ch[idx] = hh;
                    Cl[idx] = (bf16)(v - (float)hh);
                }
            }
}

// GEMM1: Y[z] = x[b] @ W[h]   (z local in half, zg = zbase+z, b=zg>>2, h=zg&3)
__global__ __launch_bounds__(256) void k_gemm1(
    const bf16* __restrict__ xh, const bf16* __restrict__ xl,
    const bf16* __restrict__ wTh, const bf16* __restrict__ wTl,
    bf16* __restrict__ Yh, bf16* __restrict__ Yl, int zbase)
{
    const int z = blockIdx.z;
    const int zg = zbase + z;
    const int b = zg >> 2, h = zg & 3;
    gemm_core<true, false, 0, D_, D_, D_, D_>(
        xh + (size_t)b * ND, xl + (size_t)b * ND,
        wTh + (size_t)h * DD, wTl + (size_t)h * DD,
        nullptr, Yh + (size_t)z * ND, Yl + (size_t)z * ND, 1.0f);
}

// GEMM2: S[z] = Y[z] @ x[b]^T * scale
__global__ __launch_bounds__(256) void k_gemm2(
    const bf16* __restrict__ Yh, const bf16* __restrict__ Yl,
    const bf16* __restrict__ xh, const bf16* __restrict__ xl,
    float* __restrict__ S, int zbase)
{
    const int z = blockIdx.z;
    const int zg = zbase + z;
    const int b = zg >> 2;
    gemm_core<true, false, 1, D_, D_, N_, D_>(
        Yh + (size_t)z * ND, Yl + (size_t)z * ND,
        xh + (size_t)b * ND, xl + (size_t)b * ND,
        S + (size_t)z * NN, nullptr, nullptr, 0.044194173824159216f);
}

// GEMM4: out[b] = 0.25 * sum_h P[b,h] @ x[b]  (K folded = 4096)
__global__ __launch_bounds__(256) void k_gemm4(
    const bf16* __restrict__ P, const bf16* __restrict__ xT,
    float* __restrict__ out)
{
    const int b = blockIdx.z;
    gemm_core<false, true, 1, N_, N_, D_, H_ * N_>(
        P + (size_t)b * H_ * NN, nullptr,
        xT + (size_t)b * ND, nullptr,
        out + (size_t)b * ND, nullptr, nullptr, 0.25f);
}

// Decompose x -> (x_hi, x_lo) bf16 and xT_hi (transposed hi, [b][d][n])
__global__ __launch_bounds__(256) void decomp_x(
    const float* __restrict__ x, bf16* __restrict__ xh,
    bf16* __restrict__ xl, bf16* __restrict__ xT)
{
    __shared__ bf16 tile[64][65];
    const int b = blockIdx.z, n0 = blockIdx.y * 64, d0 = blockIdx.x * 64;
    const float* xb = x + (size_t)b * ND;
    const int t = threadIdx.x;
#pragma unroll
    for (int p = 0; p < 16; ++p) {
        const int idx = t + p * 256;
        const int r = idx >> 6, c = idx & 63;
        const float v = xb[(size_t)(n0 + r) * D_ + d0 + c];
        const bf16 h = (bf16)v;
        const bf16 lo = (bf16)(v - (float)h);
        const size_t o = (size_t)b * ND + (size_t)(n0 + r) * D_ + d0 + c;
        xh[o] = h;
        xl[o] = lo;
        tile[r][c] = h;
    }
    __syncthreads();
#pragma unroll
    for (int p = 0; p < 16; ++p) {
        const int idx = t + p * 256;
        const int r = idx >> 6, c = idx & 63;   // r = local d, c = local n
        xT[(size_t)b * ND + (size_t)(d0 + r) * N_ + n0 + c] = tile[c][r];
    }
}

// Decompose + transpose W: W[h][d][e] -> W_hiT[h][e][d], W_loT[h][e][d]
__global__ __launch_bounds__(256) void decomp_w(
    const float* __restrict__ W, bf16* __restrict__ wTh, bf16* __restrict__ wTl)
{
    __shared__ float tw[64][65];
    const int h = blockIdx.z, d0 = blockIdx.y * 64, e0 = blockIdx.x * 64;
    const float* Wh = W + (size_t)h * DD;
    const int t = threadIdx.x;
#pragma unroll
    for (int p = 0; p < 16; ++p) {
        const int idx = t + p * 256;
        const int r = idx >> 6, c = idx & 63;
        tw[r][c] = Wh[(size_t)(d0 + r) * D_ + e0 + c];
    }
    __syncthreads();
#pragma unroll
    for (int p = 0; p < 16; ++p) {
        const int idx = t + p * 256;
        const int r = idx >> 6, c = idx & 63;   // r = local e, c = local d
        const float v = tw[c][r];
        const bf16 hh = (bf16)v;
        const size_t o = (size_t)h * DD + (size_t)(e0 + r) * D_ + d0 + c;
        wTh[o] = hh;
        wTl[o] = (bf16)(v - (float)hh);
    }
}

// Rowwise softmax on fp32 S, write bf16 P. One block per row of 1024.
__global__ __launch_bounds__(256) void softmax_rows_bf16(
    const float* __restrict__ S, bf16* __restrict__ P)
{
    const size_t row = blockIdx.x;
    const float4* p = (const float4*)(S + row * (size_t)N_);
    const int t = threadIdx.x;

    float4 v = p[t];
    float m = fmaxf(fmaxf(v.x, v.y), fmaxf(v.z, v.w));
#pragma unroll
    for (int o = 32; o > 0; o >>= 1) m = fmaxf(m, __shfl_xor(m, o));

    __shared__ float wred[4];
    const int wave = t >> 6, lane = t & 63;
    if (lane == 0) wred[wave] = m;
    __syncthreads();
    m = fmaxf(fmaxf(wred[0], wred[1]), fmaxf(wred[2], wred[3]));

    v.x = __expf(v.x - m);
    v.y = __expf(v.y - m);
    v.z = __expf(v.z - m);
    v.w = __expf(v.w - m);
    float s = v.x + v.y + v.z + v.w;
#pragma unroll
    for (int o = 32; o > 0; o >>= 1) s += __shfl_xor(s, o);
    __syncthreads();
    if (lane == 0) wred[wave] = s;
    __syncthreads();
    s = wred[0] + wred[1] + wred[2] + wred[3];

    const float inv = 1.0f / s;
    bf16x4 o4;
    o4[0] = (bf16)(v.x * inv);
    o4[1] = (bf16)(v.y * inv);
    o4[2] = (bf16)(v.z * inv);
    o4[3] = (bf16)(v.w * inv);
    *(bf16x4*)(P + row * (size_t)N_ + t * 4) = o4;
}

extern "C" void kernel_launch(void* const* d_in, const int* in_sizes, int n_in,
                              void* d_out, int out_size, void* d_ws, size_t ws_size,
                              hipStream_t stream) {
    const float* x = (const float*)d_in[0];   // [8,1024,512]
    const float* W = (const float*)d_in[1];   // [4,512,512]
    float* out = (float*)d_out;               // [8,1024,512]

    // workspace layout (188 MiB total; R1 proved >= 192 MiB available)
    char* ws = (char*)d_ws;
    const size_t MB = 1024 * 1024;
    bf16*  xh  = (bf16*)(ws + 0 * MB);     // 8 MiB
    bf16*  xl  = (bf16*)(ws + 8 * MB);     // 8 MiB
    bf16*  xT  = (bf16*)(ws + 16 * MB);    // 8 MiB
    bf16*  wTh = (bf16*)(ws + 24 * MB);    // 2 MiB
    bf16*  wTl = (bf16*)(ws + 26 * MB);    // 2 MiB
    bf16*  Yh  = (bf16*)(ws + 28 * MB);    // 16 MiB (half: 16 bh-pairs)
    bf16*  Yl  = (bf16*)(ws + 44 * MB);    // 16 MiB
    float* S   = (float*)(ws + 60 * MB);   // 64 MiB (half: 16 bh-pairs fp32)
    bf16*  P   = (bf16*)(ws + 124 * MB);   // 64 MiB (all 32 bh-pairs)

    decomp_x<<<dim3(D_ / 64, N_ / 64, B_), 256, 0, stream>>>(x, xh, xl, xT);
    decomp_w<<<dim3(D_ / 64, D_ / 64, H_), 256, 0, stream>>>(W, wTh, wTl);

    for (int half = 0; half < 2; ++half) {
        const int zbase = half * 16;
        k_gemm1<<<dim3(D_ / 128, N_ / 128, 16), 256, 0, stream>>>(
            xh, xl, wTh, wTl, Yh, Yl, zbase);
        k_gemm2<<<dim3(N_ / 128, N_ / 128, 16), 256, 0, stream>>>(
            Yh, Yl, xh, xl, S, zbase);
        softmax_rows_bf16<<<dim3(16 * N_), 256, 0, stream>>>(
            S, P + (size_t)zbase * NN);
    }
    k_gemm4<<<dim3(D_ / 128, N_ / 128, B_), 256, 0, stream>>>(P, xT, out);
}